// Round 9
// baseline (933.842 us; speedup 1.0000x reference)
//
#include <hip/hip_runtime.h>
#include <hip/hip_bf16.h>
#include <math.h>

#define B_  8
#define L_  2048
#define DIN_ 40
#define H_  128
#define NL_ 4
#define DSTATE_ 16
#define DCONV_ 4
#define DTRANK_ 8
#define DINNER_ 256
#define NHOR_ 3
#define NCLS_ 3

#define CL_ 32     // chunk length for scan
#define NC_ 64     // number of chunks (CL_*NC_ == L_)

// branchless softplus: max(x,0) + log1p(exp(-|x|))
__device__ __forceinline__ float softplus_f(float x) {
  return fmaxf(x, 0.f) + log1pf(__expf(-fabsf(x)));
}

// check A-structure: An[n] == An[0]*(n+1)  (true for A_log = log(1..16))
__device__ __forceinline__ bool a_is_arith(const float* Ag, float& An0) {
  An0 = -__expf(Ag[0]);
  if (An0 == 0.f) return false;
  bool ok = true;
#pragma unroll
  for (int n = 1; n < DSTATE_; n++) {
    float r = -__expf(Ag[n]) / An0;
    ok = ok && (fabsf(r - (float)(n + 1)) < 1e-3f);
  }
  return ok;
}

// ---------------------------------------------------------------------------
// input projection + layernorm:  h = LN(x @ W^T + b)  (one block per row)
// ---------------------------------------------------------------------------
__global__ __launch_bounds__(128) void k_in_ln(
    const float* __restrict__ x, const float* __restrict__ w,
    const float* __restrict__ bias, const float* __restrict__ g,
    const float* __restrict__ bb, float* __restrict__ hout)
{
  int row = blockIdx.x;
  int o = threadIdx.x;
  __shared__ float xs[DIN_];
  __shared__ float sm[4];
  if (o < DIN_) xs[o] = x[(size_t)row * DIN_ + o];
  __syncthreads();
  float acc = bias[o];
  const float* wr = w + (size_t)o * DIN_;
#pragma unroll
  for (int k = 0; k < DIN_; k++) acc += xs[k] * wr[k];
  float s = acc;
#pragma unroll
  for (int m = 32; m >= 1; m >>= 1) s += __shfl_xor(s, m);
  if ((o & 63) == 0) sm[o >> 6] = s;
  __syncthreads();
  float mean = (sm[0] + sm[1]) * (1.f / H_);
  float dv = acc - mean;
  float q = dv * dv;
#pragma unroll
  for (int m = 32; m >= 1; m >>= 1) q += __shfl_xor(q, m);
  if ((o & 63) == 0) sm[2 + (o >> 6)] = q;
  __syncthreads();
  float var = (sm[2] + sm[3]) * (1.f / H_);
  hout[(size_t)row * H_ + o] = dv * rsqrtf(var + 1e-5f) * g[o] + bb[o];
}

// ---------------------------------------------------------------------------
// plain layernorm over last dim 128 (only used once, before layer 0)
// ---------------------------------------------------------------------------
__global__ __launch_bounds__(128) void k_ln(
    const float* __restrict__ in, const float* __restrict__ g,
    const float* __restrict__ bb, float* __restrict__ out)
{
  int row = blockIdx.x;
  int o = threadIdx.x;
  float v = in[(size_t)row * H_ + o];
  __shared__ float sm[4];
  float s = v;
#pragma unroll
  for (int m = 32; m >= 1; m >>= 1) s += __shfl_xor(s, m);
  if ((o & 63) == 0) sm[o >> 6] = s;
  __syncthreads();
  float mean = (sm[0] + sm[1]) * (1.f / H_);
  float dv = v - mean;
  float q = dv * dv;
#pragma unroll
  for (int m = 32; m >= 1; m >>= 1) q += __shfl_xor(q, m);
  if ((o & 63) == 0) sm[2 + (o >> 6)] = q;
  __syncthreads();
  float var = (sm[2] + sm[3]) * (1.f / H_);
  out[(size_t)row * H_ + o] = dv * rsqrtf(var + 1e-5f) * g[o] + bb[o];
}

// ---------------------------------------------------------------------------
// fp32 tiled GEMM:  C = A(MxK) @ Bw(NxK)^T
// EPI: 2 = split store: col<256 -> C0[M][256], col>=256 -> C1[M][256]
// ---------------------------------------------------------------------------
template <int BM, int BN, int EPI>
__global__ __launch_bounds__(256) void gemm_tn(
    const float* __restrict__ A, const float* __restrict__ Bw,
    float* __restrict__ C0, float* __restrict__ C1,
    int M, int N, int K)
{
  constexpr int TM = BM / 16, TN = BN / 16;
  __shared__ float As[16][BM + 4];
  __shared__ float Bs[16][BN + 4];
  const int tid = threadIdx.x;
  const int tx = tid & 15, ty = tid >> 4;
  const int bm0 = blockIdx.y * BM, bn0 = blockIdx.x * BN;
  float acc[TM][TN] = {};
  constexpr int AF4 = BM / 64;
  constexpr int BF4 = BN / 64;

  for (int k0 = 0; k0 < K; k0 += 16) {
#pragma unroll
    for (int i = 0; i < AF4; i++) {
      int f = tid + i * 256;
      int r = f >> 2, kq = (f & 3) << 2;
      float4 v = *reinterpret_cast<const float4*>(&A[(size_t)(bm0 + r) * K + k0 + kq]);
      As[kq + 0][r] = v.x; As[kq + 1][r] = v.y;
      As[kq + 2][r] = v.z; As[kq + 3][r] = v.w;
    }
#pragma unroll
    for (int i = 0; i < BF4; i++) {
      int f = tid + i * 256;
      int rn = f >> 2, kq = (f & 3) << 2;
      float4 v = make_float4(0.f, 0.f, 0.f, 0.f);
      if (bn0 + rn < N)
        v = *reinterpret_cast<const float4*>(&Bw[(size_t)(bn0 + rn) * K + k0 + kq]);
      Bs[kq + 0][rn] = v.x; Bs[kq + 1][rn] = v.y;
      Bs[kq + 2][rn] = v.z; Bs[kq + 3][rn] = v.w;
    }
    __syncthreads();
#pragma unroll
    for (int k = 0; k < 16; k++) {
      float a[TM], b[TN];
#pragma unroll
      for (int i = 0; i < TM; i += 4) {
        float4 v = *reinterpret_cast<const float4*>(&As[k][ty * TM + i]);
        a[i] = v.x; a[i + 1] = v.y; a[i + 2] = v.z; a[i + 3] = v.w;
      }
#pragma unroll
      for (int j = 0; j < TN; j += 4) {
        float4 v = *reinterpret_cast<const float4*>(&Bs[k][tx * TN + j]);
        b[j] = v.x; b[j + 1] = v.y; b[j + 2] = v.z; b[j + 3] = v.w;
      }
#pragma unroll
      for (int i = 0; i < TM; i++)
#pragma unroll
        for (int j = 0; j < TN; j++) acc[i][j] += a[i] * b[j];
    }
    __syncthreads();
  }

#pragma unroll
  for (int i = 0; i < TM; i++) {
    int r = bm0 + ty * TM + i;
    int c0 = bn0 + tx * TN;
    if (c0 >= N) continue;
    float4 v = make_float4(acc[i][0], acc[i][1], acc[i][2], acc[i][3]);
    if (EPI == 0) {
      *reinterpret_cast<float4*>(&C0[(size_t)r * N + c0]) = v;
    } else {
      if (c0 < 256) *reinterpret_cast<float4*>(&C0[(size_t)r * 256 + c0]) = v;
      else          *reinterpret_cast<float4*>(&C1[(size_t)r * 256 + (c0 - 256)]) = v;
    }
  }
}

// ---------------------------------------------------------------------------
// out_proj GEMM + residual (+ fused LayerNorm for the next layer)
// ---------------------------------------------------------------------------
template <bool DO_LN>
__global__ __launch_bounds__(256) void gemm_out(
    const float* __restrict__ A, const float* __restrict__ Bw,
    float* __restrict__ H, float* __restrict__ XN,
    const float* __restrict__ g, const float* __restrict__ bb)
{
  constexpr int BM = 64, BN = 128, K = DINNER_, N = H_;
  constexpr int TM = 4, TN = 8;
  __shared__ float As[16][BM + 4];
  __shared__ float Bs[16][BN + 4];
  const int tid = threadIdx.x;
  const int tx = tid & 15, ty = tid >> 4;
  const int bm0 = blockIdx.x * BM;
  float acc[TM][TN] = {};

  for (int k0 = 0; k0 < K; k0 += 16) {
    {
      int f = tid;
      int r = f >> 2, kq = (f & 3) << 2;
      float4 v = *reinterpret_cast<const float4*>(&A[(size_t)(bm0 + r) * K + k0 + kq]);
      As[kq + 0][r] = v.x; As[kq + 1][r] = v.y;
      As[kq + 2][r] = v.z; As[kq + 3][r] = v.w;
    }
#pragma unroll
    for (int i = 0; i < 2; i++) {
      int f = tid + i * 256;
      int rn = f >> 2, kq = (f & 3) << 2;
      float4 v = *reinterpret_cast<const float4*>(&Bw[(size_t)rn * K + k0 + kq]);
      Bs[kq + 0][rn] = v.x; Bs[kq + 1][rn] = v.y;
      Bs[kq + 2][rn] = v.z; Bs[kq + 3][rn] = v.w;
    }
    __syncthreads();
#pragma unroll
    for (int k = 0; k < 16; k++) {
      float a[TM], b[TN];
      float4 av = *reinterpret_cast<const float4*>(&As[k][ty * TM]);
      a[0] = av.x; a[1] = av.y; a[2] = av.z; a[3] = av.w;
#pragma unroll
      for (int j = 0; j < TN; j += 4) {
        float4 v = *reinterpret_cast<const float4*>(&Bs[k][tx * TN + j]);
        b[j] = v.x; b[j + 1] = v.y; b[j + 2] = v.z; b[j + 3] = v.w;
      }
#pragma unroll
      for (int i = 0; i < TM; i++)
#pragma unroll
        for (int j = 0; j < TN; j++) acc[i][j] += a[i] * b[j];
    }
    __syncthreads();
  }

  float gv[TN], bv[TN];
  if (DO_LN) {
#pragma unroll
    for (int j = 0; j < TN; j += 4) {
      float4 t = *reinterpret_cast<const float4*>(&g[tx * TN + j]);
      gv[j] = t.x; gv[j+1] = t.y; gv[j+2] = t.z; gv[j+3] = t.w;
      float4 u = *reinterpret_cast<const float4*>(&bb[tx * TN + j]);
      bv[j] = u.x; bv[j+1] = u.y; bv[j+2] = u.z; bv[j+3] = u.w;
    }
  }
#pragma unroll
  for (int i = 0; i < TM; i++) {
    int r = bm0 + ty * TM + i;
    float hv[TN];
#pragma unroll
    for (int j = 0; j < TN; j += 4) {
      float4 o = *reinterpret_cast<const float4*>(&H[(size_t)r * N + tx * TN + j]);
      hv[j]   = o.x + acc[i][j];
      hv[j+1] = o.y + acc[i][j+1];
      hv[j+2] = o.z + acc[i][j+2];
      hv[j+3] = o.w + acc[i][j+3];
    }
#pragma unroll
    for (int j = 0; j < TN; j += 4)
      *reinterpret_cast<float4*>(&H[(size_t)r * N + tx * TN + j]) =
          make_float4(hv[j], hv[j+1], hv[j+2], hv[j+3]);
    if (DO_LN) {
      float s = 0.f;
#pragma unroll
      for (int j = 0; j < TN; j++) s += hv[j];
#pragma unroll
      for (int m = 1; m < 16; m <<= 1) s += __shfl_xor(s, m);
      float mean = s * (1.f / N);
      float q = 0.f;
#pragma unroll
      for (int j = 0; j < TN; j++) { float d = hv[j] - mean; q += d * d; }
#pragma unroll
      for (int m = 1; m < 16; m <<= 1) q += __shfl_xor(q, m);
      float rstd = rsqrtf(q * (1.f / N) + 1e-5f);
      float xo[TN];
#pragma unroll
      for (int j = 0; j < TN; j++) xo[j] = (hv[j] - mean) * rstd * gv[j] + bv[j];
#pragma unroll
      for (int j = 0; j < TN; j += 4)
        *reinterpret_cast<float4*>(&XN[(size_t)r * N + tx * TN + j]) =
            make_float4(xo[j], xo[j+1], xo[j+2], xo[j+3]);
    }
  }
}

// ---------------------------------------------------------------------------
// k_front: fused conv+silu -> xp-GEMM -> delta -> local chunk scan.
// Block = one (b, chunk). Writes: xp (global), ylbuf = y_local + D*xh,
// hf (chunk-final state), ss (chunk delta-sum).
// ---------------------------------------------------------------------------
__global__ __launch_bounds__(256, 4) void k_front(
    const float* __restrict__ xx, const float* __restrict__ cw,
    const float* __restrict__ cb, const float* __restrict__ xpw,
    const float* __restrict__ dtw, const float* __restrict__ dtb,
    const float* __restrict__ Ag, const float* __restrict__ Dp,
    float* __restrict__ xpg, float* __restrict__ ylbuf,
    float* __restrict__ hf, float* __restrict__ ss)
{
  int b = blockIdx.x >> 6;            // NC_=64
  int c = blockIdx.x & (NC_ - 1);
  int d = threadIdx.x;
  int row0 = b * L_ + c * CL_;

  __shared__ float xhs[CL_][256];     // 32 KB
  __shared__ float xps[CL_ * 40];     // 5 KB

  // --- conv + silu (thread owns column d, rolling window) ---
  float w0 = cw[d * DCONV_ + 0], w1 = cw[d * DCONV_ + 1];
  float w2 = cw[d * DCONV_ + 2], w3 = cw[d * DCONV_ + 3];
  float cbv = cb[d];
  float xm3 = (c > 0) ? xx[(size_t)(row0 - 3) * 256 + d] : 0.f;
  float xm2 = (c > 0) ? xx[(size_t)(row0 - 2) * 256 + d] : 0.f;
  float xm1 = (c > 0) ? xx[(size_t)(row0 - 1) * 256 + d] : 0.f;
#pragma unroll
  for (int t = 0; t < CL_; t++) {
    float xc = xx[(size_t)(row0 + t) * 256 + d];
    float a = cbv + w0 * xm3 + w1 * xm2 + w2 * xm1 + w3 * xc;
    xhs[t][d] = a / (1.f + __expf(-a));
    xm3 = xm2; xm2 = xm1; xm1 = xc;
  }
  __syncthreads();

  // --- xp = xh @ xpw^T  (CL_*40 outputs, K=256) ---
  for (int o = d; o < CL_ * 40; o += 256) {
    int t = o / 40, j = o - t * 40;
    const float* wrow = xpw + (size_t)j * 256;
    float av = 0.f;
#pragma unroll
    for (int k = 0; k < 256; k += 4) {
      float4 wv = *reinterpret_cast<const float4*>(&wrow[k]);
      float4 xv = *reinterpret_cast<const float4*>(&xhs[t][k]);
      av += xv.x * wv.x + xv.y * wv.y + xv.z * wv.z + xv.w * wv.w;
    }
    xps[o] = av;
    xpg[(size_t)row0 * 40 + o] = av;
  }
  __syncthreads();

  // --- local scan (h_init = 0) ---
  float dtw_r[DTRANK_];
#pragma unroll
  for (int k = 0; k < DTRANK_; k++) dtw_r[k] = dtw[d * DTRANK_ + k];
  float dtb_r = dtb[d];
  float Dv = Dp[d];
  float An0;
  bool fast = a_is_arith(Ag, An0);
  float h[DSTATE_] = {};
  float S = 0.f;
  size_t base = (size_t)row0 * 256 + d;
  if (fast) {
#pragma unroll
    for (int t = 0; t < CL_; t++) {
      float acc = dtb_r;
#pragma unroll
      for (int k = 0; k < DTRANK_; k++) acc += xps[t * 40 + k] * dtw_r[k];
      float dv = softplus_f(acc);
      float xv = xhs[t][d];
      S += dv;
      float dx = dv * xv;
      float E = __expf(dv * An0);
      float f = E, y = 0.f;
#pragma unroll
      for (int n = 0; n < DSTATE_; n++) {
        h[n] = f * h[n] + dx * xps[t * 40 + 8 + n];
        y += h[n] * xps[t * 40 + 24 + n];
        f *= E;
      }
      ylbuf[base + t * 256] = y + Dv * xv;
    }
  } else {
    for (int t = 0; t < CL_; t++) {
      float acc = dtb_r;
#pragma unroll
      for (int k = 0; k < DTRANK_; k++) acc += xps[t * 40 + k] * dtw_r[k];
      float dv = softplus_f(acc);
      float xv = xhs[t][d];
      S += dv;
      float dx = dv * xv;
      float y = 0.f;
      for (int n = 0; n < DSTATE_; n++) {
        float dA = __expf(dv * (-__expf(Ag[n])));
        h[n] = dA * h[n] + dx * xps[t * 40 + 8 + n];
        y += h[n] * xps[t * 40 + 24 + n];
      }
      ylbuf[base + t * 256] = y + Dv * xv;
    }
  }
  ss[(size_t)blockIdx.x * 256 + d] = S;
  float* hp = hf + ((size_t)blockIdx.x * 256 + d) * DSTATE_;
#pragma unroll
  for (int n = 0; n < DSTATE_; n += 4)
    *reinterpret_cast<float4*>(&hp[n]) = make_float4(h[n], h[n+1], h[n+2], h[n+3]);
}

// ---------------------------------------------------------------------------
// scan pass 2: sequential combine over chunks; overwrites hf with h_init
// ---------------------------------------------------------------------------
__global__ __launch_bounds__(64) void k_scan2(
    const float* __restrict__ Ag, const float* __restrict__ ss,
    float* __restrict__ hf)
{
  int gid = blockIdx.x * 64 + threadIdx.x;   // 0..32767
  int b = gid >> 12;
  int r = gid & 4095;       // d*16+n
  int d = r >> 4;
  int n = r & 15;
  float An = -__expf(Ag[n]);
  float hi = 0.f;
  for (int ct = 0; ct < NC_ / 8; ct++) {
    float f[8], s[8];
#pragma unroll
    for (int j = 0; j < 8; j++) {
      int c = ct * 8 + j;
      f[j] = hf[((size_t)(b * NC_ + c) * 4096) + r];
      s[j] = ss[(size_t)(b * NC_ + c) * 256 + d];
    }
#pragma unroll
    for (int j = 0; j < 8; j++) {
      int c = ct * 8 + j;
      float P = __expf(An * s[j]);
      hf[((size_t)(b * NC_ + c) * 4096) + r] = hi;
      hi = P * hi + f[j];
    }
  }
}

// ---------------------------------------------------------------------------
// scan pass 3 (correction form, no recurrence):
// y[t] = ylbuf[t] + sum_n exp(An_n * cumdelta_t) * h_init[n] * C_t[n]
// then in-place gate: zz[t] = y * silu(zz[t])
// ---------------------------------------------------------------------------
__global__ __launch_bounds__(256, 4) void k_scan3(
    const float* __restrict__ xpg, const float* __restrict__ dtw,
    const float* __restrict__ dtb, const float* __restrict__ Ag,
    const float* __restrict__ hf, const float* __restrict__ ylbuf,
    float* zz)
{
  int b = blockIdx.x >> 6;
  int c = blockIdx.x & (NC_ - 1);
  int d = threadIdx.x;
  int row0 = b * L_ + c * CL_;
  __shared__ float xps[CL_ * 40];
  for (int i = d; i < CL_ * 40; i += 256) xps[i] = xpg[(size_t)row0 * 40 + i];
  float dtw_r[DTRANK_];
#pragma unroll
  for (int k = 0; k < DTRANK_; k++) dtw_r[k] = dtw[d * DTRANK_ + k];
  float dtb_r = dtb[d];
  float An0;
  bool fast = a_is_arith(Ag, An0);
  __syncthreads();
  float h0[DSTATE_];
  {
    const float* hp = hf + ((size_t)blockIdx.x * 256 + d) * DSTATE_;
#pragma unroll
    for (int n = 0; n < DSTATE_; n += 4) {
      float4 v = *reinterpret_cast<const float4*>(&hp[n]);
      h0[n] = v.x; h0[n+1] = v.y; h0[n+2] = v.z; h0[n+3] = v.w;
    }
  }
  size_t base = (size_t)row0 * 256 + d;
  float cd = 0.f;
  if (fast) {
#pragma unroll
    for (int t = 0; t < CL_; t++) {
      float acc = dtb_r;
#pragma unroll
      for (int k = 0; k < DTRANK_; k++) acc += xps[t * 40 + k] * dtw_r[k];
      cd += softplus_f(acc);
      float E = __expf(cd * An0);
      float p = E, corr = 0.f;
#pragma unroll
      for (int n = 0; n < DSTATE_; n++) {
        corr += p * h0[n] * xps[t * 40 + 24 + n];
        p *= E;
      }
      float yv = ylbuf[base + t * 256] + corr;
      float zv = zz[base + t * 256];
      zz[base + t * 256] = yv * (zv / (1.f + __expf(-zv)));
    }
  } else {
    for (int t = 0; t < CL_; t++) {
      float acc = dtb_r;
#pragma unroll
      for (int k = 0; k < DTRANK_; k++) acc += xps[t * 40 + k] * dtw_r[k];
      cd += softplus_f(acc);
      float corr = 0.f;
      for (int n = 0; n < DSTATE_; n++)
        corr += __expf(cd * (-__expf(Ag[n]))) * h0[n] * xps[t * 40 + 24 + n];
      float yv = ylbuf[base + t * 256] + corr;
      float zv = zz[base + t * 256];
      zz[base + t * 256] = yv * (zv / (1.f + __expf(-zv)));
    }
  }
}

// ---------------------------------------------------------------------------
// heads: logits[b,hor,:] = gelu(feats @ w1^T + b1) @ w2^T + b2
// ---------------------------------------------------------------------------
__global__ __launch_bounds__(64) void k_heads(
    const float* __restrict__ hbuf, const float* __restrict__ w1,
    const float* __restrict__ b1, const float* __restrict__ w2,
    const float* __restrict__ b2, float* __restrict__ out)
{
  int hor = blockIdx.x, b = blockIdx.y;
  int j = threadIdx.x;
  __shared__ float fs[H_];
  __shared__ float ts[64];
  const float* fr = hbuf + ((size_t)b * L_ + (L_ - 1)) * H_;
  fs[j] = fr[j];
  fs[j + 64] = fr[j + 64];
  __syncthreads();
  float acc = b1[hor * 64 + j];
  const float* wr = w1 + (size_t)(hor * 64 + j) * H_;
#pragma unroll
  for (int k = 0; k < H_; k++) acc += fs[k] * wr[k];
  ts[j] = 0.5f * acc * (1.f + erff(acc * 0.70710678118654752f));
  __syncthreads();
  if (j < NCLS_) {
    float a2 = b2[hor * NCLS_ + j];
    const float* w2r = w2 + (size_t)(hor * NCLS_ + j) * 64;
    float s = a2;
#pragma unroll
    for (int k = 0; k < 64; k++) s += ts[k] * w2r[k];
    out[(size_t)b * (NHOR_ * NCLS_) + hor * NCLS_ + j] = s;
  }
}

// ---------------------------------------------------------------------------
extern "C" void kernel_launch(void* const* d_in, const int* in_sizes, int n_in,
                              void* d_out, int out_size, void* d_ws, size_t ws_size,
                              hipStream_t stream)
{
  const float* x            = (const float*)d_in[0];
  const float* input_proj_w = (const float*)d_in[1];
  const float* input_proj_b = (const float*)d_in[2];
  const float* input_norm_g = (const float*)d_in[3];
  const float* input_norm_b = (const float*)d_in[4];
  const float* norm_g       = (const float*)d_in[5];
  const float* norm_b       = (const float*)d_in[6];
  const float* in_proj_w    = (const float*)d_in[7];
  const float* conv_w       = (const float*)d_in[8];
  const float* conv_b       = (const float*)d_in[9];
  const float* x_proj_w     = (const float*)d_in[10];
  const float* dt_proj_w    = (const float*)d_in[11];
  const float* dt_proj_b    = (const float*)d_in[12];
  const float* A_log        = (const float*)d_in[13];
  const float* Dp           = (const float*)d_in[14];
  const float* out_proj_w   = (const float*)d_in[15];
  const float* head_w1      = (const float*)d_in[16];
  const float* head_b1      = (const float*)d_in[17];
  const float* head_w2      = (const float*)d_in[18];
  const float* head_b2      = (const float*)d_in[19];
  float* out = (float*)d_out;

  const int ROWS = B_ * L_;                 // 16384
  float* ws = (float*)d_ws;
  float* h     = ws;                          // 2,097,152 floats
  float* xn    = h  + (size_t)ROWS * H_;      // 2,097,152 (alias: hf after in_proj)
  float* xx    = xn + (size_t)ROWS * H_;      // 4,194,304
  float* zz    = xx + (size_t)ROWS * 256;     // 4,194,304 (gated in place in scan3)
  float* ylbuf = zz + (size_t)ROWS * 256;     // 4,194,304
  float* xp    = ylbuf + (size_t)ROWS * 256;  // 655,360
  float* ss    = xp + (size_t)ROWS * 40;      // 131,072
  float* hf    = xn;  // alias: xn dead after in_proj GEMM; rewritten by gemm_out AFTER scan3
  // total ~69.8 MB (< 71.6 proven)

  // h = LN(x @ W^T + b)
  k_in_ln<<<ROWS, 128, 0, stream>>>(x, input_proj_w, input_proj_b,
                                    input_norm_g, input_norm_b, h);
  // xn = LN(h) for layer 0
  k_ln<<<ROWS, 128, 0, stream>>>(h, norm_g, norm_b, xn);

  for (int l = 0; l < NL_; l++) {
    // [xx|zz] = xn @ in_proj_w^T   (M=16384, N=512, K=128), split epilogue
    gemm_tn<128, 64, 2><<<dim3(512 / 64, ROWS / 128), 256, 0, stream>>>(
        xn, in_proj_w + (size_t)l * 512 * H_, xx, zz, ROWS, 512, H_);
    // fused conv+silu -> xp -> delta -> local scan
    k_front<<<B_ * NC_, 256, 0, stream>>>(
        xx, conv_w + (size_t)l * DINNER_ * DCONV_, conv_b + (size_t)l * DINNER_,
        x_proj_w + (size_t)l * 40 * DINNER_,
        dt_proj_w + (size_t)l * DINNER_ * DTRANK_, dt_proj_b + (size_t)l * DINNER_,
        A_log + l * DSTATE_, Dp + (size_t)l * DINNER_,
        xp, ylbuf, hf, ss);
    // chunk combine
    k_scan2<<<(B_ * DINNER_ * DSTATE_) / 64, 64, 0, stream>>>(A_log + l * DSTATE_, ss, hf);
    // correction + gate (in place in zz)
    k_scan3<<<B_ * NC_, 256, 0, stream>>>(
        xp, dt_proj_w + (size_t)l * DINNER_ * DTRANK_, dt_proj_b + (size_t)l * DINNER_,
        A_log + l * DSTATE_, hf, ylbuf, zz);
    // h += zz @ out_proj_w^T (+ fused LN -> xn for next layer)
    if (l < NL_ - 1) {
      gemm_out<true><<<ROWS / 64, 256, 0, stream>>>(
          zz, out_proj_w + (size_t)l * H_ * DINNER_, h, xn,
          norm_g + (l + 1) * H_, norm_b + (l + 1) * H_);
    } else {
      gemm_out<false><<<ROWS / 64, 256, 0, stream>>>(
          zz, out_proj_w + (size_t)l * H_ * DINNER_, h, nullptr, nullptr, nullptr);
    }
  }

  k_heads<<<dim3(NHOR_, B_), 64, 0, stream>>>(h, head_w1, head_b1, head_w2, head_b2, out);
}

// Round 10
// 774.602 us; speedup vs baseline: 1.2056x; 1.2056x over previous
//
#include <hip/hip_runtime.h>
#include <hip/hip_bf16.h>
#include <math.h>

#define B_  8
#define L_  2048
#define DIN_ 40
#define H_  128
#define NL_ 4
#define DSTATE_ 16
#define DCONV_ 4
#define DTRANK_ 8
#define DINNER_ 256
#define NHOR_ 3
#define NCLS_ 3

#define CL_ 16     // chunk length for scan
#define NC_ 128    // number of chunks (CL_*NC_ == L_)

// branchless softplus: max(x,0) + log1p(exp(-|x|))
__device__ __forceinline__ float softplus_f(float x) {
  return fmaxf(x, 0.f) + log1pf(__expf(-fabsf(x)));
}

// check A-structure: An[n] == An[0]*(n+1)  (true for A_log = log(1..16))
__device__ __forceinline__ bool a_is_arith(const float* Ag, float& An0) {
  An0 = -__expf(Ag[0]);
  if (An0 == 0.f) return false;
  bool ok = true;
#pragma unroll
  for (int n = 1; n < DSTATE_; n++) {
    float r = -__expf(Ag[n]) / An0;
    ok = ok && (fabsf(r - (float)(n + 1)) < 1e-3f);
  }
  return ok;
}

// ---------------------------------------------------------------------------
// input projection + layernorm:  h = LN(x @ W^T + b)  (one block per row)
// ---------------------------------------------------------------------------
__global__ __launch_bounds__(128) void k_in_ln(
    const float* __restrict__ x, const float* __restrict__ w,
    const float* __restrict__ bias, const float* __restrict__ g,
    const float* __restrict__ bb, float* __restrict__ hout)
{
  int row = blockIdx.x;
  int o = threadIdx.x;
  __shared__ float xs[DIN_];
  __shared__ float sm[4];
  if (o < DIN_) xs[o] = x[(size_t)row * DIN_ + o];
  __syncthreads();
  float acc = bias[o];
  const float* wr = w + (size_t)o * DIN_;
#pragma unroll
  for (int k = 0; k < DIN_; k++) acc += xs[k] * wr[k];
  float s = acc;
#pragma unroll
  for (int m = 32; m >= 1; m >>= 1) s += __shfl_xor(s, m);
  if ((o & 63) == 0) sm[o >> 6] = s;
  __syncthreads();
  float mean = (sm[0] + sm[1]) * (1.f / H_);
  float dv = acc - mean;
  float q = dv * dv;
#pragma unroll
  for (int m = 32; m >= 1; m >>= 1) q += __shfl_xor(q, m);
  if ((o & 63) == 0) sm[2 + (o >> 6)] = q;
  __syncthreads();
  float var = (sm[2] + sm[3]) * (1.f / H_);
  hout[(size_t)row * H_ + o] = dv * rsqrtf(var + 1e-5f) * g[o] + bb[o];
}

// ---------------------------------------------------------------------------
// plain layernorm over last dim 128 (used once, before layer 0)
// ---------------------------------------------------------------------------
__global__ __launch_bounds__(128) void k_ln(
    const float* __restrict__ in, const float* __restrict__ g,
    const float* __restrict__ bb, float* __restrict__ out)
{
  int row = blockIdx.x;
  int o = threadIdx.x;
  float v = in[(size_t)row * H_ + o];
  __shared__ float sm[4];
  float s = v;
#pragma unroll
  for (int m = 32; m >= 1; m >>= 1) s += __shfl_xor(s, m);
  if ((o & 63) == 0) sm[o >> 6] = s;
  __syncthreads();
  float mean = (sm[0] + sm[1]) * (1.f / H_);
  float dv = v - mean;
  float q = dv * dv;
#pragma unroll
  for (int m = 32; m >= 1; m >>= 1) q += __shfl_xor(q, m);
  if ((o & 63) == 0) sm[2 + (o >> 6)] = q;
  __syncthreads();
  float var = (sm[2] + sm[3]) * (1.f / H_);
  out[(size_t)row * H_ + o] = dv * rsqrtf(var + 1e-5f) * g[o] + bb[o];
}

// ---------------------------------------------------------------------------
// fp32 tiled GEMM:  C = A(MxK) @ Bw(NxK)^T
// BMxBN tile, BK=16, 256 threads (16x16), micro-tile (BM/16)x(BN/16)
// EPI: 0 = store C0[M][N]; 2 = split: col<256 -> C0[M][256], else C1[M][256]
// ---------------------------------------------------------------------------
template <int BM, int BN, int EPI>
__global__ __launch_bounds__(256) void gemm_tn(
    const float* __restrict__ A, const float* __restrict__ Bw,
    float* __restrict__ C0, float* __restrict__ C1,
    int M, int N, int K)
{
  constexpr int TM = BM / 16, TN = BN / 16;
  __shared__ float As[16][BM + 4];
  __shared__ float Bs[16][BN + 4];
  const int tid = threadIdx.x;
  const int tx = tid & 15, ty = tid >> 4;
  const int bm0 = blockIdx.y * BM, bn0 = blockIdx.x * BN;
  float acc[TM][TN] = {};
  constexpr int AF4 = BM / 64;
  constexpr int BF4 = BN / 64;

  for (int k0 = 0; k0 < K; k0 += 16) {
#pragma unroll
    for (int i = 0; i < AF4; i++) {
      int f = tid + i * 256;
      int r = f >> 2, kq = (f & 3) << 2;
      float4 v = *reinterpret_cast<const float4*>(&A[(size_t)(bm0 + r) * K + k0 + kq]);
      As[kq + 0][r] = v.x; As[kq + 1][r] = v.y;
      As[kq + 2][r] = v.z; As[kq + 3][r] = v.w;
    }
#pragma unroll
    for (int i = 0; i < BF4; i++) {
      int f = tid + i * 256;
      int rn = f >> 2, kq = (f & 3) << 2;
      float4 v = make_float4(0.f, 0.f, 0.f, 0.f);
      if (bn0 + rn < N)
        v = *reinterpret_cast<const float4*>(&Bw[(size_t)(bn0 + rn) * K + k0 + kq]);
      Bs[kq + 0][rn] = v.x; Bs[kq + 1][rn] = v.y;
      Bs[kq + 2][rn] = v.z; Bs[kq + 3][rn] = v.w;
    }
    __syncthreads();
#pragma unroll
    for (int k = 0; k < 16; k++) {
      float a[TM], b[TN];
#pragma unroll
      for (int i = 0; i < TM; i += 4) {
        float4 v = *reinterpret_cast<const float4*>(&As[k][ty * TM + i]);
        a[i] = v.x; a[i + 1] = v.y; a[i + 2] = v.z; a[i + 3] = v.w;
      }
#pragma unroll
      for (int j = 0; j < TN; j += 4) {
        float4 v = *reinterpret_cast<const float4*>(&Bs[k][tx * TN + j]);
        b[j] = v.x; b[j + 1] = v.y; b[j + 2] = v.z; b[j + 3] = v.w;
      }
#pragma unroll
      for (int i = 0; i < TM; i++)
#pragma unroll
        for (int j = 0; j < TN; j++) acc[i][j] += a[i] * b[j];
    }
    __syncthreads();
  }

#pragma unroll
  for (int i = 0; i < TM; i++) {
    int r = bm0 + ty * TM + i;
#pragma unroll
    for (int jj = 0; jj < TN; jj += 4) {
      int c0 = bn0 + tx * TN + jj;
      if (c0 >= N) continue;
      float4 v = make_float4(acc[i][jj], acc[i][jj+1], acc[i][jj+2], acc[i][jj+3]);
      if (EPI == 0) {
        *reinterpret_cast<float4*>(&C0[(size_t)r * N + c0]) = v;
      } else {
        if (c0 < 256) *reinterpret_cast<float4*>(&C0[(size_t)r * 256 + c0]) = v;
        else          *reinterpret_cast<float4*>(&C1[(size_t)r * 256 + (c0 - 256)]) = v;
      }
    }
  }
}

// ---------------------------------------------------------------------------
// out_proj GEMM + residual (+ fused LayerNorm for the next layer)
// ---------------------------------------------------------------------------
template <bool DO_LN>
__global__ __launch_bounds__(256) void gemm_out(
    const float* __restrict__ A, const float* __restrict__ Bw,
    float* __restrict__ H, float* __restrict__ XN,
    const float* __restrict__ g, const float* __restrict__ bb)
{
  constexpr int BM = 64, BN = 128, K = DINNER_, N = H_;
  constexpr int TM = 4, TN = 8;
  __shared__ float As[16][BM + 4];
  __shared__ float Bs[16][BN + 4];
  const int tid = threadIdx.x;
  const int tx = tid & 15, ty = tid >> 4;
  const int bm0 = blockIdx.x * BM;
  float acc[TM][TN] = {};

  for (int k0 = 0; k0 < K; k0 += 16) {
    {
      int f = tid;
      int r = f >> 2, kq = (f & 3) << 2;
      float4 v = *reinterpret_cast<const float4*>(&A[(size_t)(bm0 + r) * K + k0 + kq]);
      As[kq + 0][r] = v.x; As[kq + 1][r] = v.y;
      As[kq + 2][r] = v.z; As[kq + 3][r] = v.w;
    }
#pragma unroll
    for (int i = 0; i < 2; i++) {
      int f = tid + i * 256;
      int rn = f >> 2, kq = (f & 3) << 2;
      float4 v = *reinterpret_cast<const float4*>(&Bw[(size_t)rn * K + k0 + kq]);
      Bs[kq + 0][rn] = v.x; Bs[kq + 1][rn] = v.y;
      Bs[kq + 2][rn] = v.z; Bs[kq + 3][rn] = v.w;
    }
    __syncthreads();
#pragma unroll
    for (int k = 0; k < 16; k++) {
      float a[TM], b[TN];
      float4 av = *reinterpret_cast<const float4*>(&As[k][ty * TM]);
      a[0] = av.x; a[1] = av.y; a[2] = av.z; a[3] = av.w;
#pragma unroll
      for (int j = 0; j < TN; j += 4) {
        float4 v = *reinterpret_cast<const float4*>(&Bs[k][tx * TN + j]);
        b[j] = v.x; b[j + 1] = v.y; b[j + 2] = v.z; b[j + 3] = v.w;
      }
#pragma unroll
      for (int i = 0; i < TM; i++)
#pragma unroll
        for (int j = 0; j < TN; j++) acc[i][j] += a[i] * b[j];
    }
    __syncthreads();
  }

  float gv[TN], bv[TN];
  if (DO_LN) {
#pragma unroll
    for (int j = 0; j < TN; j += 4) {
      float4 t = *reinterpret_cast<const float4*>(&g[tx * TN + j]);
      gv[j] = t.x; gv[j+1] = t.y; gv[j+2] = t.z; gv[j+3] = t.w;
      float4 u = *reinterpret_cast<const float4*>(&bb[tx * TN + j]);
      bv[j] = u.x; bv[j+1] = u.y; bv[j+2] = u.z; bv[j+3] = u.w;
    }
  }
#pragma unroll
  for (int i = 0; i < TM; i++) {
    int r = bm0 + ty * TM + i;
    float hv[TN];
#pragma unroll
    for (int j = 0; j < TN; j += 4) {
      float4 o = *reinterpret_cast<const float4*>(&H[(size_t)r * N + tx * TN + j]);
      hv[j]   = o.x + acc[i][j];
      hv[j+1] = o.y + acc[i][j+1];
      hv[j+2] = o.z + acc[i][j+2];
      hv[j+3] = o.w + acc[i][j+3];
    }
#pragma unroll
    for (int j = 0; j < TN; j += 4)
      *reinterpret_cast<float4*>(&H[(size_t)r * N + tx * TN + j]) =
          make_float4(hv[j], hv[j+1], hv[j+2], hv[j+3]);
    if (DO_LN) {
      float s = 0.f;
#pragma unroll
      for (int j = 0; j < TN; j++) s += hv[j];
#pragma unroll
      for (int m = 1; m < 16; m <<= 1) s += __shfl_xor(s, m);
      float mean = s * (1.f / N);
      float q = 0.f;
#pragma unroll
      for (int j = 0; j < TN; j++) { float d = hv[j] - mean; q += d * d; }
#pragma unroll
      for (int m = 1; m < 16; m <<= 1) q += __shfl_xor(q, m);
      float rstd = rsqrtf(q * (1.f / N) + 1e-5f);
      float xo[TN];
#pragma unroll
      for (int j = 0; j < TN; j++) xo[j] = (hv[j] - mean) * rstd * gv[j] + bv[j];
#pragma unroll
      for (int j = 0; j < TN; j += 4)
        *reinterpret_cast<float4*>(&XN[(size_t)r * N + tx * TN + j]) =
            make_float4(xo[j], xo[j+1], xo[j+2], xo[j+3]);
    }
  }
}

// ---------------------------------------------------------------------------
// causal depthwise conv (DCONV=4) + silu, reading xx[M][256] -> xh
// ---------------------------------------------------------------------------
__global__ __launch_bounds__(256) void k_conv(
    const float* __restrict__ xx, const float* __restrict__ cw,
    const float* __restrict__ cb, float* __restrict__ xh)
{
  int idx = blockIdx.x * 256 + threadIdx.x;
  int d = idx & 255;
  int bt = idx >> 8;
  int t = bt & (L_ - 1);
  float acc = cb[d];
#pragma unroll
  for (int k = 0; k < DCONV_; k++) {
    int ts = t - 3 + k;
    if (ts >= 0) acc += cw[d * DCONV_ + k] * xx[(size_t)(bt - 3 + k) * 256 + d];
  }
  xh[idx] = acc / (1.f + __expf(-acc));
}

// ---------------------------------------------------------------------------
// scan pass 1: per-chunk local state + per-chunk delta sum + y_local.
// IN-PLACE: reads xh[t], then overwrites it with ylbuf[t] = y_local + D*xh
// (read-once-then-write per element by the same thread — race-free).
// ---------------------------------------------------------------------------
__global__ __launch_bounds__(256, 4) void k_scan1y(
    float* xh_yl, const float* __restrict__ xp,
    const float* __restrict__ dtw, const float* __restrict__ dtb,
    const float* __restrict__ Ag, const float* __restrict__ Dp,
    float* __restrict__ hf, float* __restrict__ ss)
{
  int b = blockIdx.x >> 7;            // NC_=128
  int c = blockIdx.x & (NC_ - 1);
  int d = threadIdx.x;
  __shared__ float xps[CL_][40];
  {
    const float* xrow = xp + ((size_t)b * L_ + c * CL_) * 40;
    for (int i = threadIdx.x; i < CL_ * 40; i += 256) xps[i / 40][i % 40] = xrow[i];
  }
  float dtw_r[DTRANK_];
#pragma unroll
  for (int k = 0; k < DTRANK_; k++) dtw_r[k] = dtw[d * DTRANK_ + k];
  float dtb_r = dtb[d];
  float Dv = Dp[d];
  float An0;
  bool fast = a_is_arith(Ag, An0);
  __syncthreads();
  float h[DSTATE_] = {};
  float S = 0.f;
  size_t base = ((size_t)b * L_ + c * CL_) * 256 + d;
  if (fast) {
#pragma unroll
    for (int tt = 0; tt < CL_; tt++) {
      float acc = dtb_r;
#pragma unroll
      for (int k = 0; k < DTRANK_; k++) acc += xps[tt][k] * dtw_r[k];
      float dv = softplus_f(acc);
      float xv = xh_yl[base + tt * 256];
      S += dv;
      float dx = dv * xv;
      float E = __expf(dv * An0);
      float f = E, y = 0.f;
#pragma unroll
      for (int n = 0; n < DSTATE_; n++) {
        h[n] = f * h[n] + dx * xps[tt][8 + n];
        y += h[n] * xps[tt][24 + n];
        f *= E;
      }
      xh_yl[base + tt * 256] = y + Dv * xv;
    }
  } else {
    for (int tt = 0; tt < CL_; tt++) {
      float acc = dtb_r;
#pragma unroll
      for (int k = 0; k < DTRANK_; k++) acc += xps[tt][k] * dtw_r[k];
      float dv = softplus_f(acc);
      float xv = xh_yl[base + tt * 256];
      S += dv;
      float dx = dv * xv;
      float y = 0.f;
      for (int n = 0; n < DSTATE_; n++) {
        float dA = __expf(dv * (-__expf(Ag[n])));
        h[n] = dA * h[n] + dx * xps[tt][8 + n];
        y += h[n] * xps[tt][24 + n];
      }
      xh_yl[base + tt * 256] = y + Dv * xv;
    }
  }
  ss[(size_t)blockIdx.x * 256 + d] = S;
  float* hp = hf + ((size_t)blockIdx.x * 256 + d) * DSTATE_;
#pragma unroll
  for (int n = 0; n < DSTATE_; n += 4)
    *reinterpret_cast<float4*>(&hp[n]) = make_float4(h[n], h[n+1], h[n+2], h[n+3]);
}

// ---------------------------------------------------------------------------
// scan pass 2: sequential combine over chunks; overwrites hf with h_init
// ---------------------------------------------------------------------------
__global__ __launch_bounds__(64) void k_scan2(
    const float* __restrict__ Ag, const float* __restrict__ ss,
    float* __restrict__ hf)
{
  int gid = blockIdx.x * 64 + threadIdx.x;   // 0..32767
  int b = gid >> 12;
  int r = gid & 4095;       // d*16+n
  int d = r >> 4;
  int n = r & 15;
  float An = -__expf(Ag[n]);
  float hi = 0.f;
  for (int ct = 0; ct < NC_ / 8; ct++) {
    float f[8], s[8];
#pragma unroll
    for (int j = 0; j < 8; j++) {
      int c = ct * 8 + j;
      f[j] = hf[((size_t)(b * NC_ + c) * 4096) + r];
      s[j] = ss[(size_t)(b * NC_ + c) * 256 + d];
    }
#pragma unroll
    for (int j = 0; j < 8; j++) {
      int c = ct * 8 + j;
      float P = __expf(An * s[j]);
      hf[((size_t)(b * NC_ + c) * 4096) + r] = hi;
      hi = P * hi + f[j];
    }
  }
}

// ---------------------------------------------------------------------------
// scan pass 3 (correction form, no recurrence, HW-validated round 9):
// y[t] = ylbuf[t] + sum_n exp(An_n * cumdelta_t) * h_init[n] * C_t[n]
// then in-place gate: zz[t] = y * silu(zz[t])
// ---------------------------------------------------------------------------
__global__ __launch_bounds__(256, 4) void k_scan3c(
    const float* __restrict__ xpg, const float* __restrict__ dtw,
    const float* __restrict__ dtb, const float* __restrict__ Ag,
    const float* __restrict__ hf, const float* __restrict__ ylbuf,
    float* zz)
{
  int b = blockIdx.x >> 7;
  int c = blockIdx.x & (NC_ - 1);
  int d = threadIdx.x;
  int row0 = b * L_ + c * CL_;
  __shared__ float xps[CL_ * 40];
  for (int i = d; i < CL_ * 40; i += 256) xps[i] = xpg[(size_t)row0 * 40 + i];
  float dtw_r[DTRANK_];
#pragma unroll
  for (int k = 0; k < DTRANK_; k++) dtw_r[k] = dtw[d * DTRANK_ + k];
  float dtb_r = dtb[d];
  float An0;
  bool fast = a_is_arith(Ag, An0);
  __syncthreads();
  float h0[DSTATE_];
  {
    const float* hp = hf + ((size_t)blockIdx.x * 256 + d) * DSTATE_;
#pragma unroll
    for (int n = 0; n < DSTATE_; n += 4) {
      float4 v = *reinterpret_cast<const float4*>(&hp[n]);
      h0[n] = v.x; h0[n+1] = v.y; h0[n+2] = v.z; h0[n+3] = v.w;
    }
  }
  size_t base = (size_t)row0 * 256 + d;
  float cd = 0.f;
  if (fast) {
#pragma unroll
    for (int t = 0; t < CL_; t++) {
      float acc = dtb_r;
#pragma unroll
      for (int k = 0; k < DTRANK_; k++) acc += xps[t * 40 + k] * dtw_r[k];
      cd += softplus_f(acc);
      float E = __expf(cd * An0);
      float p = E, corr = 0.f;
#pragma unroll
      for (int n = 0; n < DSTATE_; n++) {
        corr += p * h0[n] * xps[t * 40 + 24 + n];
        p *= E;
      }
      float yv = ylbuf[base + t * 256] + corr;
      float zv = zz[base + t * 256];
      zz[base + t * 256] = yv * (zv / (1.f + __expf(-zv)));
    }
  } else {
    for (int t = 0; t < CL_; t++) {
      float acc = dtb_r;
#pragma unroll
      for (int k = 0; k < DTRANK_; k++) acc += xps[t * 40 + k] * dtw_r[k];
      cd += softplus_f(acc);
      float corr = 0.f;
      for (int n = 0; n < DSTATE_; n++)
        corr += __expf(cd * (-__expf(Ag[n]))) * h0[n] * xps[t * 40 + 24 + n];
      float yv = ylbuf[base + t * 256] + corr;
      float zv = zz[base + t * 256];
      zz[base + t * 256] = yv * (zv / (1.f + __expf(-zv)));
    }
  }
}

// ---------------------------------------------------------------------------
// heads: logits[b,hor,:] = gelu(feats @ w1^T + b1) @ w2^T + b2
// ---------------------------------------------------------------------------
__global__ __launch_bounds__(64) void k_heads(
    const float* __restrict__ hbuf, const float* __restrict__ w1,
    const float* __restrict__ b1, const float* __restrict__ w2,
    const float* __restrict__ b2, float* __restrict__ out)
{
  int hor = blockIdx.x, b = blockIdx.y;
  int j = threadIdx.x;
  __shared__ float fs[H_];
  __shared__ float ts[64];
  const float* fr = hbuf + ((size_t)b * L_ + (L_ - 1)) * H_;
  fs[j] = fr[j];
  fs[j + 64] = fr[j + 64];
  __syncthreads();
  float acc = b1[hor * 64 + j];
  const float* wr = w1 + (size_t)(hor * 64 + j) * H_;
#pragma unroll
  for (int k = 0; k < H_; k++) acc += fs[k] * wr[k];
  ts[j] = 0.5f * acc * (1.f + erff(acc * 0.70710678118654752f));
  __syncthreads();
  if (j < NCLS_) {
    float a2 = b2[hor * NCLS_ + j];
    const float* w2r = w2 + (size_t)(hor * NCLS_ + j) * 64;
    float s = a2;
#pragma unroll
    for (int k = 0; k < 64; k++) s += ts[k] * w2r[k];
    out[(size_t)b * (NHOR_ * NCLS_) + hor * NCLS_ + j] = s;
  }
}

// ---------------------------------------------------------------------------
extern "C" void kernel_launch(void* const* d_in, const int* in_sizes, int n_in,
                              void* d_out, int out_size, void* d_ws, size_t ws_size,
                              hipStream_t stream)
{
  const float* x            = (const float*)d_in[0];
  const float* input_proj_w = (const float*)d_in[1];
  const float* input_proj_b = (const float*)d_in[2];
  const float* input_norm_g = (const float*)d_in[3];
  const float* input_norm_b = (const float*)d_in[4];
  const float* norm_g       = (const float*)d_in[5];
  const float* norm_b       = (const float*)d_in[6];
  const float* in_proj_w    = (const float*)d_in[7];
  const float* conv_w       = (const float*)d_in[8];
  const float* conv_b       = (const float*)d_in[9];
  const float* x_proj_w     = (const float*)d_in[10];
  const float* dt_proj_w    = (const float*)d_in[11];
  const float* dt_proj_b    = (const float*)d_in[12];
  const float* A_log        = (const float*)d_in[13];
  const float* Dp           = (const float*)d_in[14];
  const float* out_proj_w   = (const float*)d_in[15];
  const float* head_w1      = (const float*)d_in[16];
  const float* head_b1      = (const float*)d_in[17];
  const float* head_w2      = (const float*)d_in[18];
  const float* head_b2      = (const float*)d_in[19];
  float* out = (float*)d_out;

  const int ROWS = B_ * L_;                 // 16384
  float* ws = (float*)d_ws;
  float* h    = ws;                          // 8.39 MB
  float* xn   = h  + (size_t)ROWS * H_;      // 8.39 MB
  float* xx   = xn + (size_t)ROWS * H_;      // 16.8 MB (alias: hf after conv)
  float* zz   = xx + (size_t)ROWS * 256;     // 16.8 MB (gated in place in scan3)
  float* xh   = zz + (size_t)ROWS * 256;     // 16.8 MB (becomes ylbuf in scan1, in place)
  float* xp   = xh + (size_t)ROWS * 256;     // 2.62 MB
  float* ss   = xp + (size_t)ROWS * 40;      // 1.05 MB
  float* hf   = xx;                          // alias: xx dead after k_conv
  // total ~70.8 MB (round-8-proven layout)

  // h = LN(x @ W^T + b);  xn = LN(h) for layer 0
  k_in_ln<<<ROWS, 128, 0, stream>>>(x, input_proj_w, input_proj_b,
                                    input_norm_g, input_norm_b, h);
  k_ln<<<ROWS, 128, 0, stream>>>(h, norm_g, norm_b, xn);

  for (int l = 0; l < NL_; l++) {
    // [xx|zz] = xn @ in_proj_w^T   (M=16384, N=512, K=128), 128x128 tile
    gemm_tn<128, 128, 2><<<dim3(512 / 128, ROWS / 128), 256, 0, stream>>>(
        xn, in_proj_w + (size_t)l * 512 * H_, xx, zz, ROWS, 512, H_);
    // conv + silu
    k_conv<<<ROWS, 256, 0, stream>>>(xx, conv_w + (size_t)l * DINNER_ * DCONV_,
                                     conv_b + (size_t)l * DINNER_, xh);
    // xp = xh @ x_proj_w^T   (N=40, K=256)
    gemm_tn<64, 64, 0><<<dim3(1, ROWS / 64), 256, 0, stream>>>(
        xh, x_proj_w + (size_t)l * 40 * DINNER_, xp, nullptr, ROWS, 40, DINNER_);
    // scan pass 1: local scan + y_local (ylbuf in place over xh)
    k_scan1y<<<B_ * NC_, 256, 0, stream>>>(xh, xp,
        dt_proj_w + (size_t)l * DINNER_ * DTRANK_, dt_proj_b + (size_t)l * DINNER_,
        A_log + l * DSTATE_, Dp + (size_t)l * DINNER_, hf, ss);
    // chunk combine
    k_scan2<<<(B_ * DINNER_ * DSTATE_) / 64, 64, 0, stream>>>(A_log + l * DSTATE_, ss, hf);
    // correction + gate (in place in zz); reads ylbuf(=xh), xp
    k_scan3c<<<B_ * NC_, 256, 0, stream>>>(
        xp, dt_proj_w + (size_t)l * DINNER_ * DTRANK_, dt_proj_b + (size_t)l * DINNER_,
        A_log + l * DSTATE_, hf, xh, zz);
    // h += zz @ out_proj_w^T (+ fused LN -> xn for next layer)
    if (l < NL_ - 1) {
      gemm_out<true><<<ROWS / 64, 256, 0, stream>>>(
          zz, out_proj_w + (size_t)l * H_ * DINNER_, h, xn,
          norm_g + (l + 1) * H_, norm_b + (l + 1) * H_);
    } else {
      gemm_out<false><<<ROWS / 64, 256, 0, stream>>>(
          zz, out_proj_w + (size_t)l * H_ * DINNER_, h, nullptr, nullptr, nullptr);
    }
  }

  k_heads<<<dim3(NHOR_, B_), 64, 0, stream>>>(h, head_w1, head_b1, head_w2, head_b2, out);
}